// Round 9
// baseline (126.396 us; speedup 1.0000x reference)
//
#include <hip/hip_runtime.h>
#include <hip/hip_bf16.h>

// Problem constants (B,G,D,H,K,V) = (4, 2048, 128, 8, 16, 16)
#define GG 2048
#define DD 128
#define HH 8
#define BH 32

typedef _Float16 h2 __attribute__((ext_vector_type(2)));
typedef _Float16 h4 __attribute__((ext_vector_type(4)));
typedef _Float16 h8 __attribute__((ext_vector_type(8)));
typedef __attribute__((ext_vector_type(4))) float f32x4;
typedef unsigned short u16;
typedef unsigned int   u32;
typedef unsigned char  u8;
typedef unsigned long long u64;

// 0.25 (=1/sqrt(16)) * log2(e): folded into W_Q so softmax uses raw exp2.
#define QSCALE 0.36067376022224085f

// ws layout (f16), ~8.6 MB total
#define OFF_Q 0u            // f16 [BH][G][16] (scaled)   2 MB
#define OFF_K (2u << 20)    // f16 [BH][G][16]            2 MB
#define OFF_V (4u << 20)    // f16 [BH][16][G] (V^T)      2 MB
#define OFF_M (6u << 20)    // u8  mbt[16][G][16] transposed mask bits  512 KB
#define OFF_H 6815744u      // f16 h [B][G][128]          2 MB
#define OFF_W 8912896u      // f16 Wc [H][48][128]       96 KB

#if __has_builtin(__builtin_amdgcn_exp2f)
#define EXP2F(x) __builtin_amdgcn_exp2f(x)
#else
#define EXP2F(x) exp2f(x)
#endif

// Legacy K=16 f16 MFMA (no underscore before f16 — gfx908-era naming).
#define MFMA16(a, b, c) __builtin_amdgcn_mfma_f32_16x16x16f16(a, b, c, 0, 0, 0)

// ---------------------------------------------------------------------------
// Kernel 1 (fused streaming prep):
//   blocks [0,512):      h fp32 -> f16            (8 elems/thread)
//   blocks [512,704):    W pack -> Wc[h][48][128] f16, QSCALE in Q cols
//   blocks [704,2752):   mask int32 -> TRANSPOSED byte map mbt[g8][q][16]
// ---------------------------------------------------------------------------
__global__ __launch_bounds__(256) void prep_kernel(
    const float* __restrict__ h, const int* __restrict__ mask,
    const float* __restrict__ WQ, const float* __restrict__ WK,
    const float* __restrict__ WV,
    _Float16* __restrict__ hF, _Float16* __restrict__ Wc, u8* __restrict__ mbt)
{
  const int blk = blockIdx.x, tid = threadIdx.x;
  if (blk < 512) {                       // ---- h convert ----
    int i = (blk * 256 + tid) * 8;
    float4 a = *(const float4*)(h + i);
    float4 b = *(const float4*)(h + i + 4);
    h8 o = { (_Float16)a.x, (_Float16)a.y, (_Float16)a.z, (_Float16)a.w,
             (_Float16)b.x, (_Float16)b.y, (_Float16)b.z, (_Float16)b.w };
    *(h8*)(hF + i) = o;
  } else if (blk < 704) {                // ---- W pack ----
    int j = (blk - 512) * 256 + tid;     // [0, 49152)
    int hh = j / (48 * DD);
    int r  = j % (48 * DD);
    int n  = r / DD;
    int d  = r % DD;
    float val;
    if (n < 16)      val = WQ[((size_t)hh * DD + d) * 16 + n] * QSCALE;
    else if (n < 32) val = WK[((size_t)hh * DD + d) * 16 + (n - 16)];
    else             val = WV[((size_t)hh * DD + d) * 16 + (n - 32)];
    Wc[j] = (_Float16)val;
  } else {                               // ---- mask -> transposed byte map ----
    int t = (blk - 704) * 256 + tid;     // [0, 524288)
    const int* m = mask + (size_t)t * 8;
    int4 m0 = *(const int4*)m;
    int4 m1 = *(const int4*)(m + 4);
    u32 byte = (m0.x > 0) | ((m0.y > 0) << 1) | ((m0.z > 0) << 2) | ((m0.w > 0) << 3)
             | ((m1.x > 0) << 4) | ((m1.y > 0) << 5) | ((m1.z > 0) << 6) | ((m1.w > 0) << 7);
    int q  = t >> 8;          // mask row
    int k8 = t & 255;         // byte index within row (keys k8*8..+7)
    mbt[(size_t)(k8 >> 4) * (GG * 16) + (size_t)q * 16 + (k8 & 15)] = (u8)byte;
  }
}

// ---------------------------------------------------------------------------
// Kernel 2: MFMA projection (f16). One wave per (bh, 64-row g-tile):
// [64x128] x [128x48] via 4 m-tiles x 3 n-tiles x 4 k-steps of 16x16x32_f16.
// ---------------------------------------------------------------------------
__global__ __launch_bounds__(64) void proj_mfma(
    const _Float16* __restrict__ hF, const _Float16* __restrict__ Wc,
    _Float16* __restrict__ Qh, _Float16* __restrict__ Kh, _Float16* __restrict__ Vt)
{
  const int bh = blockIdx.x >> 5;
  const int gt = blockIdx.x & 31;
  const int b  = bh >> 3;
  const int hh = bh & (HH - 1);
  const int lane = threadIdx.x;
  const int col  = lane & 15;
  const int quad = lane >> 4;
  const int g0 = gt * 64;

  const _Float16* hb = hF + (size_t)b * GG * DD;
  const _Float16* W  = Wc + (size_t)hh * 48 * DD;

  f32x4 acc[4][3];
  #pragma unroll
  for (int mt = 0; mt < 4; ++mt)
    #pragma unroll
    for (int nt = 0; nt < 3; ++nt)
      acc[mt][nt] = (f32x4){0.f, 0.f, 0.f, 0.f};

  #pragma unroll
  for (int s = 0; s < 4; ++s) {
    h8 a[4], bw[3];
    #pragma unroll
    for (int mt = 0; mt < 4; ++mt)
      a[mt] = *(const h8*)(hb + (size_t)(g0 + mt * 16 + col) * DD + s * 32 + quad * 8);
    #pragma unroll
    for (int nt = 0; nt < 3; ++nt)
      bw[nt] = *(const h8*)(W + (size_t)(nt * 16 + col) * DD + s * 32 + quad * 8);
    #pragma unroll
    for (int mt = 0; mt < 4; ++mt)
      #pragma unroll
      for (int nt = 0; nt < 3; ++nt)
        acc[mt][nt] = __builtin_amdgcn_mfma_f32_16x16x32_f16(a[mt], bw[nt], acc[mt][nt], 0, 0, 0);
  }

  #pragma unroll
  for (int mt = 0; mt < 4; ++mt) {
    #pragma unroll
    for (int r = 0; r < 4; ++r) {
      int g = g0 + mt * 16 + quad * 4 + r;
      Qh[((size_t)bh * GG + g) * 16 + col] = (_Float16)acc[mt][0][r];
      Kh[((size_t)bh * GG + g) * 16 + col] = (_Float16)acc[mt][1][r];
      Vt[((size_t)bh * 16 + col) * GG + g] = (_Float16)acc[mt][2][r];
    }
  }
}

// ---------------------------------------------------------------------------
// Kernel 3: flash attention, in-block split-K.
// 512-thread blocks: 8 waves = 4 q-tile-pairs (32 q each) x 2 key-halves
// (1024 keys each) -> 4096 waves = 4 waves/SIMD (r8 was grid-limited to 2,
// OccupancyPercent 17.6, VALUBusy 53). Partials merge via one LDS exchange +
// single __syncthreads at the end. Denominator comes FREE from a ones-MFMA
// (A==1 -> every lane/reg accumulates sum_k P[k][col]) on the 13%-busy MFMA
// pipe — kills the per-tile fp32 adds and the end butterfly, and makes the
// denominator use the same f16-rounded p as the numerator.
// bh = blockIdx & 31 keeps each bh's K/V on one XCD (r8's fix, FETCH 17.7->5.2MB).
// ---------------------------------------------------------------------------
__global__ __launch_bounds__(512, 4) void attn_kernel(
    const _Float16* __restrict__ Qh, const _Float16* __restrict__ Kh,
    const _Float16* __restrict__ Vt, const u8* __restrict__ mbt,
    float* __restrict__ out)
{
  __shared__ float Lacc[4][32][17];   // [q-group][q-in-wave][vdim pad 17]
  __shared__ float Ll[4][32];
  const int tid = threadIdx.x, wv = tid >> 6, lane = tid & 63;
  const int g   = wv & 3;             // q-tile-pair index
  const int kh  = wv >> 2;            // key half
  const int col = lane & 15, quad = lane >> 4;
  const int bh = blockIdx.x & 31;     // XCD swizzle: same bh -> same XCD
  const int qb = (blockIdx.x >> 5) * 128 + g * 32;

  // Q B-frags (16x16x16): B[k=dim][n=q]: n=col, k=quad*4+j -> 8B loads
  const h4 qf0 = *(const h4*)(Qh + ((size_t)bh * GG + qb + col) * 16 + quad * 4);
  const h4 qf1 = *(const h4*)(Qh + ((size_t)bh * GG + qb + 16 + col) * 16 + quad * 4);

  const _Float16* Kb = Kh + (size_t)bh * GG * 16;
  const _Float16* Vb = Vt + ((size_t)bh * 16 + col) * GG;   // row col = vdim
  const u8* mr0 = mbt + (size_t)(qb + col) * 16;            // + g8*(GG*16)
  const u8* mr1 = mbt + (size_t)(qb + 16 + col) * 16;

  f32x4 acc0 = {0.f,0.f,0.f,0.f}, acc1 = {0.f,0.f,0.f,0.f};
  f32x4 lacc0 = {0.f,0.f,0.f,0.f}, lacc1 = {0.f,0.f,0.f,0.f};
  const f32x4 cinit = {-4.f, -4.f, -4.f, -4.f};
  const h4 ones = {(_Float16)1.f, (_Float16)1.f, (_Float16)1.f, (_Float16)1.f};
  const int shq = quad * 4;

  for (int g8 = 0; g8 < 8; ++g8) {          // this half's 8 groups of 128 keys
    const int gg = kh * 8 + g8;
    const size_t goff = (size_t)gg * (GG * 16);
    uint4 mv0 = *(const uint4*)(mr0 + goff);   // 128 mask bits, q row 0
    uint4 mv1 = *(const uint4*)(mr1 + goff);   // 128 mask bits, q row 1
    u64 wa0 = (u64)mv0.x | ((u64)mv0.y << 32);
    u64 wa1 = (u64)mv0.z | ((u64)mv0.w << 32);
    u64 wb0 = (u64)mv1.x | ((u64)mv1.y << 32);
    u64 wb1 = (u64)mv1.z | ((u64)mv1.w << 32);

    // batch-issue the group's 16 fragment loads (in-order consumption)
    h4 kf[8], vf[8];
    #pragma unroll
    for (int t = 0; t < 8; ++t) {
      const int kb = gg * 128 + t * 16;
      kf[t] = *(const h4*)(Kb + (size_t)(kb + col) * 16 + shq);
      vf[t] = *(const h4*)(Vb + kb + shq);
    }

    #pragma unroll
    for (int t = 0; t < 8; ++t) {
      // S^T[key=quad*4+r][q=col], pre-shifted by -4 (cancels in softmax)
      f32x4 s0 = MFMA16(kf[t], qf0, cinit);
      f32x4 s1 = MFMA16(kf[t], qf1, cinit);
      const int sh = (t & 3) * 16 + shq;
      u32 b0 = (u32)(((t < 4) ? wa0 : wa1) >> sh) & 0xFu;
      u32 b1 = (u32)(((t < 4) ? wb0 : wb1) >> sh) & 0xFu;

      float a0 = (b0 & 1u) ? 0.f : EXP2F(s0[0]);
      float a1 = (b0 & 2u) ? 0.f : EXP2F(s0[1]);
      float a2 = (b0 & 4u) ? 0.f : EXP2F(s0[2]);
      float a3 = (b0 & 8u) ? 0.f : EXP2F(s0[3]);
      float c0 = (b1 & 1u) ? 0.f : EXP2F(s1[0]);
      float c1 = (b1 & 2u) ? 0.f : EXP2F(s1[1]);
      float c2 = (b1 & 4u) ? 0.f : EXP2F(s1[2]);
      float c3 = (b1 & 8u) ? 0.f : EXP2F(s1[3]);

      // P pack: exactly the PV B-operand (k=key=quad*4+j, n=q=col)
      h2 pa01 = __builtin_bit_cast(h2, __builtin_amdgcn_cvt_pkrtz(a0, a1));
      h2 pa23 = __builtin_bit_cast(h2, __builtin_amdgcn_cvt_pkrtz(a2, a3));
      h4 pf0 = __builtin_shufflevector(pa01, pa23, 0, 1, 2, 3);
      h2 pc01 = __builtin_bit_cast(h2, __builtin_amdgcn_cvt_pkrtz(c0, c1));
      h2 pc23 = __builtin_bit_cast(h2, __builtin_amdgcn_cvt_pkrtz(c2, c3));
      h4 pf1 = __builtin_shufflevector(pc01, pc23, 0, 1, 2, 3);

      // O^T[vdim][q] += V^T · P  (V-frag shared by both q-tiles)
      acc0 = MFMA16(vf[t], pf0, acc0);
      acc1 = MFMA16(vf[t], pf1, acc1);
      // denominator: A==1 -> every lane/reg gets sum_k P[k][col]
      lacc0 = MFMA16(ones, pf0, lacc0);
      lacc1 = MFMA16(ones, pf1, lacc1);
    }
  }

  const float l0 = lacc0[0];   // l for q=qb+col, this key half
  const float l1 = lacc1[0];   // l for q=qb+16+col

  if (kh == 0) {               // half 0 publishes partials
    #pragma unroll
    for (int r = 0; r < 4; ++r) {
      Lacc[g][col][shq + r]      = acc0[r];
      Lacc[g][col + 16][shq + r] = acc1[r];
    }
    if (quad == 0) { Ll[g][col] = l0; Ll[g][col + 16] = l1; }
  }
  __syncthreads();
  if (kh == 1) {               // half 1 combines + stores
    float la = Ll[g][col] + l0;
    float lb = Ll[g][col + 16] + l1;
    float ra = (la > 0.f) ? (1.f / la) : 0.f;  // all-masked row -> 0 (ref)
    float rb = (lb > 0.f) ? (1.f / lb) : 0.f;
    float4 o0, o1;
    o0.x = (Lacc[g][col][shq + 0] + acc0[0]) * ra;
    o0.y = (Lacc[g][col][shq + 1] + acc0[1]) * ra;
    o0.z = (Lacc[g][col][shq + 2] + acc0[2]) * ra;
    o0.w = (Lacc[g][col][shq + 3] + acc0[3]) * ra;
    o1.x = (Lacc[g][col + 16][shq + 0] + acc1[0]) * rb;
    o1.y = (Lacc[g][col + 16][shq + 1] + acc1[1]) * rb;
    o1.z = (Lacc[g][col + 16][shq + 2] + acc1[2]) * rb;
    o1.w = (Lacc[g][col + 16][shq + 3] + acc1[3]) * rb;
    *(float4*)(out + ((size_t)bh * GG + qb + col) * 16 + shq) = o0;
    *(float4*)(out + ((size_t)bh * GG + qb + 16 + col) * 16 + shq) = o1;
  }
}

// ---------------------------------------------------------------------------
extern "C" void kernel_launch(void* const* d_in, const int* in_sizes, int n_in,
                              void* d_out, int out_size, void* d_ws, size_t ws_size,
                              hipStream_t stream) {
  const float* h    = (const float*)d_in[0];
  const int*   mask = (const int*)d_in[1];
  const float* WQ   = (const float*)d_in[2];
  const float* WK   = (const float*)d_in[3];
  const float* WV   = (const float*)d_in[4];
  float* out = (float*)d_out;
  char* ws = (char*)d_ws;     // uses ~8.6 MB
  _Float16* Qh = (_Float16*)(ws + OFF_Q);
  _Float16* Kh = (_Float16*)(ws + OFF_K);
  _Float16* Vt = (_Float16*)(ws + OFF_V);
  u8*       mbt = (u8*)(ws + OFF_M);
  _Float16* hF = (_Float16*)(ws + OFF_H);
  _Float16* Wc = (_Float16*)(ws + OFF_W);

  hipLaunchKernelGGL(prep_kernel, dim3(2752), dim3(256), 0, stream,
                     h, mask, WQ, WK, WV, hF, Wc, mbt);
  hipLaunchKernelGGL(proj_mfma, dim3(BH * (GG / 64)), dim3(64), 0, stream,
                     hF, Wc, Qh, Kh, Vt);
  hipLaunchKernelGGL(attn_kernel, dim3(BH * (GG / 128)), dim3(512), 0, stream,
                     Qh, Kh, Vt, mbt, out);
}

// Round 10
// 112.223 us; speedup vs baseline: 1.1263x; 1.1263x over previous
//
#include <hip/hip_runtime.h>
#include <hip/hip_bf16.h>

// Problem constants (B,G,D,H,K,V) = (4, 2048, 128, 8, 16, 16)
#define GG 2048
#define DD 128
#define HH 8
#define BH 32

typedef _Float16 h2 __attribute__((ext_vector_type(2)));
typedef _Float16 h4 __attribute__((ext_vector_type(4)));
typedef _Float16 h8 __attribute__((ext_vector_type(8)));
typedef __attribute__((ext_vector_type(4))) float f32x4;
typedef unsigned short u16;
typedef unsigned int   u32;
typedef unsigned char  u8;
typedef unsigned long long u64;

// 0.25 (=1/sqrt(16)) * log2(e): folded into W_Q so softmax uses raw exp2.
#define QSCALE 0.36067376022224085f

// ws layout: 6.5 MB
#define OFF_Q  0u           // f16 Qh [BH][G][16] (scaled)                    2 MB
#define OFF_KV (2u << 20)   // u8  KVp [BH][16 tiles][8192]: K(128x16) | V^T  4 MB
#define OFF_M  (6u << 20)   // u8  mbt [16][G][16] transposed mask bits     512 KB

#if __has_builtin(__builtin_amdgcn_exp2f)
#define EXP2F(x) __builtin_amdgcn_exp2f(x)
#else
#define EXP2F(x) exp2f(x)
#endif

// Legacy K=16 f16 MFMA (no underscore before f16 — gfx908-era naming).
#define MFMA16(a, b, c) __builtin_amdgcn_mfma_f32_16x16x16f16(a, b, c, 0, 0, 0)

static __device__ __forceinline__ u16 f16b(float x) {
  return __builtin_bit_cast(u16, (_Float16)x);
}

// ---------------------------------------------------------------------------
// Kernel 1 (fused prep):
//  blocks [0,256):   MFMA projection. Reads fp32 h + fp32 W (W packed to LDS
//                    as f16, QSCALE folded into Q cols). Writes Qh and the
//                    packed KV tiles: per (bh, 128-key tile) 8 KB contiguous:
//                    K [key 128][dim 16] f16, then V^T [vdim 16][128 keys]
//                    with per-row chunk swizzle (chunk j of row v stored at
//                    position (j+v)&31) so attn's vf ds_read is conflict-floor.
//  blocks [256,2304): mask int32 -> transposed byte map mbt[g8][q][16].
// ---------------------------------------------------------------------------
__global__ __launch_bounds__(256) void prep_kernel(
    const float* __restrict__ h, const int* __restrict__ mask,
    const float* __restrict__ WQ, const float* __restrict__ WK,
    const float* __restrict__ WV,
    _Float16* __restrict__ Qh, u8* __restrict__ KVp, u8* __restrict__ mbt)
{
  const int blk = blockIdx.x, tid = threadIdx.x;

  if (blk >= 256) {                      // ---- mask -> transposed byte map ----
    int t = (blk - 256) * 256 + tid;     // [0, 524288)
    const int* m = mask + (size_t)t * 8;
    int4 m0 = *(const int4*)m;
    int4 m1 = *(const int4*)(m + 4);
    u32 byte = (m0.x > 0) | ((m0.y > 0) << 1) | ((m0.z > 0) << 2) | ((m0.w > 0) << 3)
             | ((m1.x > 0) << 4) | ((m1.y > 0) << 5) | ((m1.z > 0) << 6) | ((m1.w > 0) << 7);
    int q  = t >> 8;          // mask row
    int k8 = t & 255;         // byte index within row (keys k8*8..+7)
    mbt[(size_t)(k8 >> 4) * (GG * 16) + (size_t)q * 16 + (k8 & 15)] = (u8)byte;
    return;
  }

  // ---- projection: 8 blocks/bh, 4 waves/block, 64 g-rows/wave ----
  __shared__ _Float16 Wl[48 * 136];      // [n 48][d 128 pad 136]
  const int bh = blk >> 3, b = bh >> 3, hh = bh & (HH - 1);

  #pragma unroll
  for (int m = 0; m < 3; ++m) {
    const float* W = (m == 0 ? WQ : (m == 1 ? WK : WV)) + (size_t)hh * DD * 16;
    const float sc = (m == 0) ? QSCALE : 1.0f;
    #pragma unroll
    for (int i = 0; i < 2; ++i) {
      int j4 = i * 256 + tid;
      float4 v = ((const float4*)W)[j4];
      int j = j4 * 4, d = j >> 4, n0 = m * 16 + (j & 15);
      Wl[(n0 + 0) * 136 + d] = (_Float16)(v.x * sc);
      Wl[(n0 + 1) * 136 + d] = (_Float16)(v.y * sc);
      Wl[(n0 + 2) * 136 + d] = (_Float16)(v.z * sc);
      Wl[(n0 + 3) * 136 + d] = (_Float16)(v.w * sc);
    }
  }
  __syncthreads();

  const int wave = tid >> 6, lane = tid & 63;
  const int col = lane & 15, quad = lane >> 4;
  const int g0 = ((blk & 7) * 4 + wave) * 64;
  const float* hb = h + (size_t)b * GG * DD;

  f32x4 acc[4][3];
  #pragma unroll
  for (int mt = 0; mt < 4; ++mt)
    #pragma unroll
    for (int nt = 0; nt < 3; ++nt)
      acc[mt][nt] = (f32x4){0.f, 0.f, 0.f, 0.f};

  #pragma unroll
  for (int s = 0; s < 4; ++s) {
    h8 a[4], bw[3];
    #pragma unroll
    for (int mt = 0; mt < 4; ++mt) {
      const float* src = hb + (size_t)(g0 + mt * 16 + col) * DD + s * 32 + quad * 8;
      float4 x = ((const float4*)src)[0];
      float4 y = ((const float4*)src)[1];
      a[mt] = (h8){ (_Float16)x.x, (_Float16)x.y, (_Float16)x.z, (_Float16)x.w,
                    (_Float16)y.x, (_Float16)y.y, (_Float16)y.z, (_Float16)y.w };
    }
    #pragma unroll
    for (int nt = 0; nt < 3; ++nt)
      bw[nt] = *(const h8*)&Wl[(nt * 16 + col) * 136 + s * 32 + quad * 8];
    #pragma unroll
    for (int mt = 0; mt < 4; ++mt)
      #pragma unroll
      for (int nt = 0; nt < 3; ++nt)
        acc[mt][nt] = __builtin_amdgcn_mfma_f32_16x16x32_f16(a[mt], bw[nt], acc[mt][nt], 0, 0, 0);
  }

  u8* kvb = KVp + (size_t)bh * 16 * 8192;
  #pragma unroll
  for (int mt = 0; mt < 4; ++mt) {
    #pragma unroll
    for (int r = 0; r < 4; ++r) {
      int g = g0 + mt * 16 + quad * 4 + r;
      Qh[((size_t)bh * GG + g) * 16 + col] = (_Float16)acc[mt][0][r];
      int gi = g & 127;
      u8* tb = kvb + (size_t)(g >> 7) * 8192;
      *(u16*)(tb + gi * 32 + col * 2) = f16b(acc[mt][1][r]);                 // K
      *(u16*)(tb + 4096 + col * 256 + ((((gi >> 2) + col) & 31) * 8)
                 + (g & 3) * 2) = f16b(acc[mt][2][r]);                       // V^T swizzled
    }
  }
}

// ---------------------------------------------------------------------------
// Kernel 2: flash attention with cooperative double-buffered LDS staging.
// Block = 256 thr (4 waves, 16 q each, 64 q/block); grid 1024 = 4 blocks/CU
// -> 4 waves/SIMD with independent per-block barriers. Per 128-key tile:
// linear 8 KB KV copy (2 uint4/thread; next-tile global loads issued at loop
// top, consumed by ds_write just before the single barrier -> latency hidden
// by compute). Fragments come from LDS (ds_read_b64, conflict-floor layouts)
// — fixes r6-r9's uncovered per-tile L2 round trips (compiler refused to keep
// batched global loads live: VGPR 48/60). S^T via 16x16x16 f16 (C/D layout ==
// PV B layout, register-direct P), denominator via ones-MFMA, XCD swizzle.
// ---------------------------------------------------------------------------
__global__ __launch_bounds__(256, 4) void attn_kernel(
    const _Float16* __restrict__ Qh, const u8* __restrict__ KVp,
    const u8* __restrict__ mbt, float* __restrict__ out)
{
  __shared__ __align__(16) u8 kv[2][8192];
  const int tid = threadIdx.x, wv = tid >> 6, lane = tid & 63;
  const int col = lane & 15, quad = lane >> 4;
  const int bh = blockIdx.x & 31;            // XCD swizzle: same bh -> same XCD
  const int qb = (blockIdx.x >> 5) * 64 + wv * 16;

  // Q B-frag (16x16x16): n=col, k=quad*4+j -> 8B load
  const h4 qf = *(const h4*)(Qh + ((size_t)bh * GG + qb + col) * 16 + quad * 4);
  const u8* kvsrc = KVp + (size_t)bh * 16 * 8192;
  const u8* mrow  = mbt + (size_t)(qb + col) * 16;

  // prologue: stage tile 0 + its mask
  {
    uint4 p0 = *(const uint4*)(kvsrc + tid * 32);
    uint4 p1 = *(const uint4*)(kvsrc + tid * 32 + 16);
    *(uint4*)(kv[0] + tid * 32) = p0;
    *(uint4*)(kv[0] + tid * 32 + 16) = p1;
  }
  uint4 mv = *(const uint4*)mrow;
  __syncthreads();

  f32x4 acc = {0.f,0.f,0.f,0.f}, lacc = {0.f,0.f,0.f,0.f};
  const f32x4 cinit = {-4.f, -4.f, -4.f, -4.f};
  const h4 ones = {(_Float16)1.f, (_Float16)1.f, (_Float16)1.f, (_Float16)1.f};

  for (int kt = 0; kt < 16; ++kt) {
    uint4 ns0, ns1, nmv;
    if (kt < 15) {                           // next-tile loads: in flight all compute
      const u8* nsrc = kvsrc + (size_t)(kt + 1) * 8192 + tid * 32;
      ns0 = *(const uint4*)nsrc;
      ns1 = *(const uint4*)(nsrc + 16);
      nmv = *(const uint4*)(mrow + (size_t)(kt + 1) * (GG * 16));
    }

    const u8* cur = kv[kt & 1];
    const _Float16* ldsK = (const _Float16*)cur;
    const u8* ldsV = cur + 4096;
    u64 w0 = (u64)mv.x | ((u64)mv.y << 32);
    u64 w1 = (u64)mv.z | ((u64)mv.w << 32);

    #pragma unroll
    for (int st = 0; st < 8; ++st) {
      // K: A[m=key st*16+col][k=dim quad*4..+3]
      h4 kf = *(const h4*)(ldsK + (size_t)(st * 16 + col) * 16 + quad * 4);
      // V^T: A[m=vdim col][k=key st*16+quad*4..+3], chunk-swizzled row
      h4 vf = *(const h4*)(ldsV + col * 256 + (((st * 4 + quad + col) & 31) * 8));

      f32x4 s = MFMA16(kf, qf, cinit);       // S^T[key][q=col], -4 shift
      const int sh = (st & 3) * 16 + quad * 4;
      u32 bits = (u32)(((st < 4) ? w0 : w1) >> sh) & 0xFu;
      float p0 = (bits & 1u) ? 0.f : EXP2F(s[0]);
      float p1 = (bits & 2u) ? 0.f : EXP2F(s[1]);
      float p2 = (bits & 4u) ? 0.f : EXP2F(s[2]);
      float p3 = (bits & 8u) ? 0.f : EXP2F(s[3]);

      h2 a01 = __builtin_bit_cast(h2, __builtin_amdgcn_cvt_pkrtz(p0, p1));
      h2 a23 = __builtin_bit_cast(h2, __builtin_amdgcn_cvt_pkrtz(p2, p3));
      h4 pf = __builtin_shufflevector(a01, a23, 0, 1, 2, 3);

      acc  = MFMA16(vf, pf, acc);            // O^T[vdim][q]
      lacc = MFMA16(ones, pf, lacc);         // denominator (free, MFMA pipe)
    }

    if (kt < 15) {
      // write buffer (kt+1)&1: its iter-(kt-1) readers all passed the last
      // barrier -> single barrier per tile is sufficient.
      u8* nb = kv[(kt + 1) & 1];
      *(uint4*)(nb + tid * 32) = ns0;
      *(uint4*)(nb + tid * 32 + 16) = ns1;
      mv = nmv;
      __syncthreads();
    }
  }

  const float l = lacc[0];                   // sum_k P[k][col], all 2048 keys
  const float rl = (l > 0.f) ? (1.f / l) : 0.f;   // all-masked row -> 0 (ref)
  float4 o = { acc[0] * rl, acc[1] * rl, acc[2] * rl, acc[3] * rl };
  *(float4*)(out + ((size_t)bh * GG + qb + col) * 16 + quad * 4) = o;
}

// ---------------------------------------------------------------------------
extern "C" void kernel_launch(void* const* d_in, const int* in_sizes, int n_in,
                              void* d_out, int out_size, void* d_ws, size_t ws_size,
                              hipStream_t stream) {
  const float* h    = (const float*)d_in[0];
  const int*   mask = (const int*)d_in[1];
  const float* WQ   = (const float*)d_in[2];
  const float* WK   = (const float*)d_in[3];
  const float* WV   = (const float*)d_in[4];
  float* out = (float*)d_out;
  char* ws = (char*)d_ws;     // uses 6.5 MB
  _Float16* Qh  = (_Float16*)(ws + OFF_Q);
  u8*       KVp = (u8*)(ws + OFF_KV);
  u8*       mbt = (u8*)(ws + OFF_M);

  hipLaunchKernelGGL(prep_kernel, dim3(256 + GG * GG / (256 * 8)), dim3(256), 0, stream,
                     h, mask, WQ, WK, WV, Qh, KVp, mbt);
  hipLaunchKernelGGL(attn_kernel, dim3(BH * (GG / 64)), dim3(256), 0, stream,
                     Qh, KVp, mbt, out);
}